// Round 5
// baseline (529.584 us; speedup 1.0000x reference)
//
#include <hip/hip_runtime.h>

#define HID 10
#define TT  2048
#define BB  4096

__device__ __forceinline__ float fast_tanh(float x) {
    // tanh(x) = 1 - 2/(exp2(x*2*log2e) + 1); saturates correctly at +-inf
    float e = exp2f(x * 2.885390081777926814f);
    float r = __builtin_amdgcn_rcpf(e + 1.0f);
    return fmaf(-2.0f, r, 1.0f);
}

// 16 lanes per batch row (lane = hidden-unit index), TWO real rows per wave
// (groups 0,1); groups 2,3 mirror them as dummies (stores masked). 2048
// single-wave blocks -> 2 waves/SIMD so cross-wave interleave hides the LDS
// round-trip latency and the single-wave issue-cadence gaps (R1..R4 all
// pinned at 1 wave/SIMD = structural stall floor).
__global__ void __launch_bounds__(64) rnn_kernel(
    const float* __restrict__ x,    const float* __restrict__ hs,
    const float* __restrict__ Wih0, const float* __restrict__ Whh0,
    const float* __restrict__ bih0, const float* __restrict__ bhh0,
    const float* __restrict__ Wih1, const float* __restrict__ Whh1,
    const float* __restrict__ bih1, const float* __restrict__ bhh1,
    const float* __restrict__ Wout, const float* __restrict__ boutp,
    float* __restrict__ out)
{
    const int tid  = threadIdx.x;
    const int lane = tid & 15;          // hidden unit index
    const int grp  = tid >> 4;          // 0,1 real; 2,3 dummy mirrors
    const int gr   = grp & 1;           // mirrored group id
    const bool real = (grp < 2);
    const int row  = blockIdx.x * 2 + gr;

    // 48-float stride => group bases 16 banks apart => <=2-way aliasing (free)
    __shared__ float lds[4 * 48];
    float* hbuf = &lds[grp * 48];

    // ---- per-lane weight rows (lanes >= HID get zeros; never read back) ----
    float whh0[HID], wih1[HID], whh1[HID], wout[HID];
    float wih0i, b0c, b1c;
    if (lane < HID) {
        #pragma unroll
        for (int j = 0; j < HID; ++j) {
            whh0[j] = Whh0[lane * HID + j];
            wih1[j] = Wih1[lane * HID + j];
            whh1[j] = Whh1[lane * HID + j];
        }
        wih0i = Wih0[lane];
        b0c   = bih0[lane] + bhh0[lane];
        b1c   = bih1[lane] + bhh1[lane];
    } else {
        #pragma unroll
        for (int j = 0; j < HID; ++j) { whh0[j] = 0.f; wih1[j] = 0.f; whh1[j] = 0.f; }
        wih0i = 0.f; b0c = 0.f; b1c = 0.f;
    }
    #pragma unroll
    for (int j = 0; j < HID; ++j) wout[j] = Wout[j];
    const float bo = boutp[0];

    // ---- initial state: every lane holds the full h0/h1 vectors ----
    float h0v[HID], h1v[HID];
    #pragma unroll
    for (int j = 0; j < HID; ++j) {
        h0v[j] = hs[row * HID + j];
        h1v[j] = hs[BB * HID + row * HID + j];
    }

    const float* xrow = x   + (size_t)row * TT;
    float*       orow = out + (size_t)row * TT;

    // software-pipelined x prefetch (one 8-step body ahead)
    float4 xa = *(const float4*)(xrow);
    float4 xb = *(const float4*)(xrow + 4);

    float h0n = 0.f, h1n = 0.f;

    for (int t0 = 0; t0 < TT; t0 += 8) {
        int tp = t0 + 8; tp = (tp > TT - 8) ? (TT - 8) : tp;   // clamped prefetch
        float4 xc = *(const float4*)(xrow + tp);
        float4 xd = *(const float4*)(xrow + tp + 4);

        float xw[8] = {xa.x, xa.y, xa.z, xa.w, xb.x, xb.y, xb.z, xb.w};
        float o[8];

        #pragma unroll
        for (int k = 0; k < 8; ++k) {
            // ---------- layer 0 ----------
            float a0 = fmaf(xw[k], wih0i, b0c), a0b = 0.f;   // two chains
            #pragma unroll
            for (int j = 0; j < HID; j += 2) {
                a0  = fmaf(whh0[j],   h0v[j],   a0);
                a0b = fmaf(whh0[j+1], h0v[j+1], a0b);
            }
            h0n = fast_tanh(a0 + a0b);
            hbuf[lane] = h0n;
            __builtin_amdgcn_wave_barrier();
            const float4 p0 = *(const float4*)&hbuf[0];
            const float4 p1 = *(const float4*)&hbuf[4];
            const float2 p2 = *(const float2*)&hbuf[8];
            // layer-1 old-h1 half first: fills the LDS read latency
            float a1 = b1c, a1b = 0.f;
            #pragma unroll
            for (int j = 0; j < HID; j += 2) {
                a1  = fmaf(whh1[j],   h1v[j],   a1);
                a1b = fmaf(whh1[j+1], h1v[j+1], a1b);
            }
            h0v[0]=p0.x; h0v[1]=p0.y; h0v[2]=p0.z; h0v[3]=p0.w;
            h0v[4]=p1.x; h0v[5]=p1.y; h0v[6]=p1.z; h0v[7]=p1.w;
            h0v[8]=p2.x; h0v[9]=p2.y;
            #pragma unroll
            for (int j = 0; j < HID; j += 2) {
                a1  = fmaf(wih1[j],   h0v[j],   a1);
                a1b = fmaf(wih1[j+1], h0v[j+1], a1b);
            }
            h1n = fast_tanh(a1 + a1b);
            hbuf[16 + lane] = h1n;
            __builtin_amdgcn_wave_barrier();
            const float4 q0 = *(const float4*)&hbuf[16];
            const float4 q1 = *(const float4*)&hbuf[20];
            const float2 q2 = *(const float2*)&hbuf[24];
            h1v[0]=q0.x; h1v[1]=q0.y; h1v[2]=q0.z; h1v[3]=q0.w;
            h1v[4]=q1.x; h1v[5]=q1.y; h1v[6]=q1.z; h1v[7]=q1.w;
            h1v[8]=q2.x; h1v[9]=q2.y;
            // ---------- fused output linear ----------
            float ov = bo, ovb = 0.f;
            #pragma unroll
            for (int j = 0; j < HID; j += 2) {
                ov  = fmaf(wout[j],   h1v[j],   ov);
                ovb = fmaf(wout[j+1], h1v[j+1], ovb);
            }
            o[k] = ov + ovb;
        }

        if (real && lane == 0) {
            *(float4*)(orow + t0)     = make_float4(o[0], o[1], o[2], o[3]);
            *(float4*)(orow + t0 + 4) = make_float4(o[4], o[5], o[6], o[7]);
        }
        xa = xc; xb = xd;
    }

    // final hidden state: [2, B, H] appended after the B*T outputs
    if (real && lane < HID) {
        out[(size_t)BB * TT + (size_t)row * HID + lane]                     = h0n;
        out[(size_t)BB * TT + (size_t)BB * HID + (size_t)row * HID + lane]  = h1n;
    }
}

extern "C" void kernel_launch(void* const* d_in, const int* in_sizes, int n_in,
                              void* d_out, int out_size, void* d_ws, size_t ws_size,
                              hipStream_t stream) {
    const float* x    = (const float*)d_in[0];
    const float* hs   = (const float*)d_in[1];
    const float* Wih0 = (const float*)d_in[2];
    const float* Whh0 = (const float*)d_in[3];
    const float* bih0 = (const float*)d_in[4];
    const float* bhh0 = (const float*)d_in[5];
    const float* Wih1 = (const float*)d_in[6];
    const float* Whh1 = (const float*)d_in[7];
    const float* bih1 = (const float*)d_in[8];
    const float* bhh1 = (const float*)d_in[9];
    const float* Wout = (const float*)d_in[10];
    const float* bout = (const float*)d_in[11];
    float* out = (float*)d_out;

    dim3 grid(BB / 2), block(64);
    hipLaunchKernelGGL(rnn_kernel, grid, block, 0, stream,
        x, hs, Wih0, Whh0, bih0, bhh0, Wih1, Whh1, bih1, bhh1, Wout, bout, out);
}

// Round 6
// 336.637 us; speedup vs baseline: 1.5732x; 1.5732x over previous
//
#include <hip/hip_runtime.h>

#define HID 10
#define TT  2048
#define BB  4096

typedef float f2 __attribute__((ext_vector_type(2)));

__device__ __forceinline__ f2 pkmul(f2 a, f2 b) {
    f2 d;
    asm("v_pk_mul_f32 %0, %1, %2" : "=v"(d) : "v"(a), "v"(b));
    return d;
}
__device__ __forceinline__ f2 pkfma(f2 a, f2 b, f2 c) {
    f2 d;
    asm("v_pk_fma_f32 %0, %1, %2, %3" : "=v"(d) : "v"(a), "v"(b), "v"(c));
    return d;
}

__device__ __forceinline__ float fast_tanh(float x) {
    // tanh(x) = 1 - 2/(exp2(x*2*log2e) + 1); saturates correctly at +-inf
    float e = exp2f(x * 2.885390081777926814f);
    float r = __builtin_amdgcn_rcpf(e + 1.0f);
    return fmaf(-2.0f, r, 1.0f);
}

// 16 lanes/row (lane = hidden unit; lane 10 carries the output dot), 4 rows
// per wave, 1024 waves = 1 wave/SIMD. R1 dataflow (LDS broadcast), slimmed:
//  - packed v_pk_fma_f32 matvecs (f2-resident weights + state)
//  - out(t) folded into lane 10's L1 chain (Whh1row:=Wout, bias:=b_out),
//    captured pre-tanh with a 1-step lag; stored as aligned quads w/ carry
//  - broadcast state consumed directly from ds_read_b64 results (no commits)
__global__ void __launch_bounds__(64) rnn_kernel(
    const float* __restrict__ x,    const float* __restrict__ hs,
    const float* __restrict__ Wih0, const float* __restrict__ Whh0,
    const float* __restrict__ bih0, const float* __restrict__ bhh0,
    const float* __restrict__ Wih1, const float* __restrict__ Whh1,
    const float* __restrict__ bih1, const float* __restrict__ bhh1,
    const float* __restrict__ Wout, const float* __restrict__ boutp,
    float* __restrict__ out)
{
    const int tid  = threadIdx.x;
    const int lane = tid & 15;          // hidden unit slot
    const int grp  = tid >> 4;          // row within wave
    const int row  = blockIdx.x * 4 + grp;
    const bool act    = (lane < HID);
    const bool olane  = (lane == HID);  // lane 10 = output-dot rider

    // 48-float stride => group bases 16 banks apart => <=2-way aliasing (free)
    __shared__ float lds[4 * 48];
    float* hb = &lds[grp * 48];         // [0..15] h0 slots, [16..31] h1 slots

    // ---- f2-packed weights ----
    f2 whh0p[5], wih1p[5], whh1p[5];
    float wih0i, b0c, b1c;
    if (act) {
        #pragma unroll
        for (int j = 0; j < 5; ++j) {
            whh0p[j] = f2{Whh0[lane * HID + 2*j], Whh0[lane * HID + 2*j + 1]};
            wih1p[j] = f2{Wih1[lane * HID + 2*j], Wih1[lane * HID + 2*j + 1]};
            whh1p[j] = f2{Whh1[lane * HID + 2*j], Whh1[lane * HID + 2*j + 1]};
        }
        wih0i = Wih0[lane];
        b0c   = bih0[lane] + bhh0[lane];
        b1c   = bih1[lane] + bhh1[lane];
    } else {
        #pragma unroll
        for (int j = 0; j < 5; ++j) {
            whh0p[j] = f2{0.f, 0.f}; wih1p[j] = f2{0.f, 0.f}; whh1p[j] = f2{0.f, 0.f};
        }
        wih0i = 0.f; b0c = 0.f; b1c = 0.f;
        if (olane) {   // ride the L1 h1-half chain: pre-tanh acc == out(t-1)
            #pragma unroll
            for (int j = 0; j < 5; ++j)
                whh1p[j] = f2{Wout[2*j], Wout[2*j + 1]};
            b1c = boutp[0];
        }
    }

    // ---- broadcast state (every lane holds full h0/h1 as 5 f2 each) ----
    f2 H0[5], H1[5];
    #pragma unroll
    for (int j = 0; j < 5; ++j) {
        H0[j] = f2{hs[row * HID + 2*j], hs[row * HID + 2*j + 1]};
        H1[j] = f2{hs[BB * HID + row * HID + 2*j], hs[BB * HID + row * HID + 2*j + 1]};
    }

    const float* xrow = x   + (size_t)row * TT;
    float*       orow = out + (size_t)row * TT;

    float4 xa = *(const float4*)(xrow);
    float4 xb = *(const float4*)(xrow + 4);

    float h0own = 0.f, h1own = 0.f;
    float P5 = 0.f, P6 = 0.f, P7 = 0.f;    // carried captures out(8b-4..8b-2)

    for (int b = 0; b < TT / 8; ++b) {
        const int t0 = b * 8;
        int tp = t0 + 8; tp = (tp > TT - 8) ? (TT - 8) : tp;
        const float4 xc = *(const float4*)(xrow + tp);
        const float4 xd = *(const float4*)(xrow + tp + 4);

        float cap[8];   // lane10: cap[k] = out(8b+k-1)

        #pragma unroll
        for (int k = 0; k < 8; ++k) {
            const float xk = (k == 0) ? xa.x : (k == 1) ? xa.y : (k == 2) ? xa.z
                           : (k == 3) ? xa.w : (k == 4) ? xb.x : (k == 5) ? xb.y
                           : (k == 6) ? xb.z : xb.w;

            // ---------- layer 0 ----------
            const float a0 = fmaf(xk, wih0i, b0c);
            f2 acc = pkmul(whh0p[0], H0[0]);
            acc = pkfma(whh0p[1], H0[1], acc);
            acc = pkfma(whh0p[2], H0[2], acc);
            acc = pkfma(whh0p[3], H0[3], acc);
            acc = pkfma(whh0p[4], H0[4], acc);
            const float h0n = fast_tanh((a0 + acc.x) + acc.y);
            hb[lane] = h0n;
            __builtin_amdgcn_wave_barrier();
            f2 nh0[5];
            #pragma unroll
            for (int j = 0; j < 5; ++j) nh0[j] = *(const f2*)&hb[2*j];

            // ---------- layer 1: h1-half first (covers h0-read latency) -----
            f2 bcc = pkmul(whh1p[0], H1[0]);
            bcc = pkfma(whh1p[1], H1[1], bcc);
            bcc = pkfma(whh1p[2], H1[2], bcc);
            bcc = pkfma(whh1p[3], H1[3], bcc);
            bcc = pkfma(whh1p[4], H1[4], bcc);
            bcc = pkfma(wih1p[0], nh0[0], bcc);
            bcc = pkfma(wih1p[1], nh0[1], bcc);
            bcc = pkfma(wih1p[2], nh0[2], bcc);
            bcc = pkfma(wih1p[3], nh0[3], bcc);
            bcc = pkfma(wih1p[4], nh0[4], bcc);
            const float s1 = (b1c + bcc.x) + bcc.y;
            cap[k] = s1;                       // lane10: out(t-1)
            const float h1n = fast_tanh(s1);
            hb[16 + lane] = h1n;
            __builtin_amdgcn_wave_barrier();
            #pragma unroll
            for (int j = 0; j < 5; ++j) H1[j] = *(const f2*)&hb[16 + 2*j];
            #pragma unroll
            for (int j = 0; j < 5; ++j) H0[j] = nh0[j];
            h0own = h0n; h1own = h1n;

            // aligned quad stores with 1-step lag
            if (k == 0 && b > 0 && olane) {
                *(float4*)(orow + 8*b - 4) = make_float4(P5, P6, P7, cap[0]);
            }
            if (k == 4 && olane) {
                *(float4*)(orow + 8*b) = make_float4(cap[1], cap[2], cap[3], cap[4]);
            }
        }

        P5 = cap[5]; P6 = cap[6]; P7 = cap[7];
        xa = xc; xb = xd;
    }

    // ---- epilogue: out(2047) from final h1 (lane10's whh1p == Wout) ----
    f2 cc = pkmul(whh1p[0], H1[0]);
    cc = pkfma(whh1p[1], H1[1], cc);
    cc = pkfma(whh1p[2], H1[2], cc);
    cc = pkfma(whh1p[3], H1[3], cc);
    cc = pkfma(whh1p[4], H1[4], cc);
    const float ofin = (b1c + cc.x) + cc.y;
    if (olane) {
        *(float4*)(orow + TT - 4) = make_float4(P5, P6, P7, ofin);
    }

    // final hidden state: [2, B, H] appended after B*T outputs
    if (act) {
        out[(size_t)BB * TT + (size_t)row * HID + lane]                    = h0own;
        out[(size_t)BB * TT + (size_t)BB * HID + (size_t)row * HID + lane] = h1own;
    }
}

extern "C" void kernel_launch(void* const* d_in, const int* in_sizes, int n_in,
                              void* d_out, int out_size, void* d_ws, size_t ws_size,
                              hipStream_t stream) {
    const float* x    = (const float*)d_in[0];
    const float* hs   = (const float*)d_in[1];
    const float* Wih0 = (const float*)d_in[2];
    const float* Whh0 = (const float*)d_in[3];
    const float* bih0 = (const float*)d_in[4];
    const float* bhh0 = (const float*)d_in[5];
    const float* Wih1 = (const float*)d_in[6];
    const float* Whh1 = (const float*)d_in[7];
    const float* bih1 = (const float*)d_in[8];
    const float* bhh1 = (const float*)d_in[9];
    const float* Wout = (const float*)d_in[10];
    const float* bout = (const float*)d_in[11];
    float* out = (float*)d_out;

    dim3 grid(BB / 4), block(64);
    hipLaunchKernelGGL(rnn_kernel, grid, block, 0, stream,
        x, hs, Wih0, Whh0, bih0, bhh0, Wih1, Whh1, bih1, bhh1, Wout, bout, out);
}

// Round 8
// 298.124 us; speedup vs baseline: 1.7764x; 1.1292x over previous
//
#include <hip/hip_runtime.h>

#define HID 10
#define TT  2048
#define BB  4096

typedef float f2 __attribute__((ext_vector_type(2)));

static __device__ __forceinline__ f2 pkmul(f2 a, f2 b) {
    f2 d; asm("v_pk_mul_f32 %0, %1, %2" : "=v"(d) : "v"(a), "v"(b)); return d;
}
static __device__ __forceinline__ f2 pkfma(f2 a, f2 b, f2 c) {
    f2 d; asm("v_pk_fma_f32 %0, %1, %2, %3" : "=v"(d) : "v"(a), "v"(b), "v"(c)); return d;
}

__device__ __forceinline__ float fast_tanh(float x) {
    // tanh(x) = 1 - 2/(exp2(x*2*log2e) + 1); saturates correctly at +-inf
    float e = exp2f(x * 2.885390081777926814f);
    float r = __builtin_amdgcn_rcpf(e + 1.0f);
    return fmaf(-2.0f, r, 1.0f);
}

// Producer-consumer wave specialization, 4 rows/block (block = 128 thr = 2 waves):
//   wave A (tid<64):  layer-0 recurrence only; publishes h0(t) into an 8-slot
//                     LDS ring (per row), self-broadcast via same ring.
//   wave B (tid>=64): layer-1 + fused output, consuming h0 with a 4-step lag;
//                     lane 10 rides Wout/b_out on its L1 chain. NOTE: the
//                     rider's capture at step t is out(t-1) (it sees h1(t-1)),
//                     so stores carry a 1-step lag (P1..P3 + epilogue) -- this
//                     was R7's off-by-one bug.
// One __syncthreads per 4-step block (~513 total). 2048 waves = 2/SIMD, all
// real work: A and B latencies hide under each other's issue streams.
__global__ void __launch_bounds__(128) rnn_kernel(
    const float* __restrict__ x,    const float* __restrict__ hs,
    const float* __restrict__ Wih0, const float* __restrict__ Whh0,
    const float* __restrict__ bih0, const float* __restrict__ bhh0,
    const float* __restrict__ Wih1, const float* __restrict__ Whh1,
    const float* __restrict__ bih1, const float* __restrict__ bhh1,
    const float* __restrict__ Wout, const float* __restrict__ boutp,
    float* __restrict__ out)
{
    const int tid   = threadIdx.x;
    const bool isA  = tid < 64;
    const int lane  = tid & 15;          // hidden unit slot
    const int grp   = (tid >> 4) & 3;    // row within block
    const int row   = blockIdx.x * 4 + grp;
    const bool act  = (lane < HID);
    const bool olane = (lane == HID);    // B: output-dot rider

    // per row: h0 ring [8][16] + h1 buf [16] = 144 floats (group bases 16
    // banks apart pairwise -> <=2-way aliasing, free; broadcast reads free)
    __shared__ float lds[4 * 144];
    float* ring = &lds[grp * 144];
    float* h1b  = &lds[grp * 144 + 128];

    const float* xrow = x   + (size_t)row * TT;
    float*       orow = out + (size_t)row * TT;

    // ---- role state (loaded under role branch) ----
    f2 whh0p[5]; float wih0i = 0.f, b0c = 0.f;   // A weights
    f2 H0[5];                                     // A: h0(t-1) broadcast
    float4 xq = make_float4(0.f, 0.f, 0.f, 0.f);
    float h0own = 0.f;
    f2 wih1p[5], whh1p[5]; float b1c = 0.f;       // B weights
    f2 H1[5];                                     // B: h1(t-1) broadcast
    float h1own = 0.f;
    float P1 = 0.f, P2 = 0.f, P3 = 0.f;           // B: carried out(tb..tb+2)

    if (isA) {
        #pragma unroll
        for (int j = 0; j < 5; ++j)
            whh0p[j] = act ? f2{Whh0[lane*HID + 2*j], Whh0[lane*HID + 2*j+1]}
                           : f2{0.f, 0.f};
        wih0i = act ? Wih0[lane] : 0.f;
        b0c   = act ? (bih0[lane] + bhh0[lane]) : 0.f;
        #pragma unroll
        for (int j = 0; j < 5; ++j)
            H0[j] = f2{hs[row*HID + 2*j], hs[row*HID + 2*j+1]};
        xq = *(const float4*)(xrow);
    } else {
        #pragma unroll
        for (int j = 0; j < 5; ++j) {
            wih1p[j] = act ? f2{Wih1[lane*HID + 2*j], Wih1[lane*HID + 2*j+1]}
                           : f2{0.f, 0.f};
            whh1p[j] = act ? f2{Whh1[lane*HID + 2*j], Whh1[lane*HID + 2*j+1]}
                     : (olane ? f2{Wout[2*j], Wout[2*j+1]} : f2{0.f, 0.f});
        }
        b1c = act ? (bih1[lane] + bhh1[lane]) : (olane ? boutp[0] : 0.f);
        #pragma unroll
        for (int j = 0; j < 5; ++j)
            H1[j] = f2{hs[BB*HID + row*HID + 2*j], hs[BB*HID + row*HID + 2*j+1]};
    }

    for (int m = 0; m <= TT / 4; ++m) {
        if (isA) {
            if (m < TT / 4) {
                const int mn = (m + 1 < TT / 4) ? m + 1 : m;
                const float4 xn = *(const float4*)(xrow + 4 * mn);  // next block
                const float xs[4] = {xq.x, xq.y, xq.z, xq.w};
                #pragma unroll
                for (int k = 0; k < 4; ++k) {
                    const int i = 4 * m + k;
                    f2 acc = pkmul(whh0p[0], H0[0]);
                    acc = pkfma(whh0p[1], H0[1], acc);
                    acc = pkfma(whh0p[2], H0[2], acc);
                    acc = pkfma(whh0p[3], H0[3], acc);
                    acc = pkfma(whh0p[4], H0[4], acc);
                    const float a0 = fmaf(xs[k], wih0i, b0c);
                    h0own = fast_tanh((a0 + acc.x) + acc.y);
                    ring[(i & 7) * 16 + lane] = h0own;
                    __builtin_amdgcn_wave_barrier();
                    const float* rb = &ring[(i & 7) * 16];
                    const float4 r0 = *(const float4*)(rb);
                    const float4 r1 = *(const float4*)(rb + 4);
                    const f2     r2 = *(const f2*)(rb + 8);
                    H0[0] = f2{r0.x, r0.y}; H0[1] = f2{r0.z, r0.w};
                    H0[2] = f2{r1.x, r1.y}; H0[3] = f2{r1.z, r1.w};
                    H0[4] = r2;
                }
                xq = xn;
            }
        } else {
            if (m > 0) {
                const int tb = 4 * (m - 1);
                // read this block's 4 h0 slots (A wrote them last iteration)
                f2 hb[4][5];
                #pragma unroll
                for (int k = 0; k < 4; ++k) {
                    const float* rb = &ring[((tb + k) & 7) * 16];
                    const float4 r0 = *(const float4*)(rb);
                    const float4 r1 = *(const float4*)(rb + 4);
                    const f2     r2 = *(const f2*)(rb + 8);
                    hb[k][0] = f2{r0.x, r0.y}; hb[k][1] = f2{r0.z, r0.w};
                    hb[k][2] = f2{r1.x, r1.y}; hb[k][3] = f2{r1.z, r1.w};
                    hb[k][4] = r2;
                }
                float c0 = 0.f, c1 = 0.f, c2 = 0.f, c3 = 0.f;
                #pragma unroll
                for (int k = 0; k < 4; ++k) {
                    // step t = tb+k. rider capture s1(lane10) = out(t-1).
                    f2 bcc = pkmul(wih1p[0], hb[k][0]);
                    bcc = pkfma(wih1p[1], hb[k][1], bcc);
                    bcc = pkfma(wih1p[2], hb[k][2], bcc);
                    bcc = pkfma(wih1p[3], hb[k][3], bcc);
                    bcc = pkfma(wih1p[4], hb[k][4], bcc);
                    bcc = pkfma(whh1p[0], H1[0], bcc);
                    bcc = pkfma(whh1p[1], H1[1], bcc);
                    bcc = pkfma(whh1p[2], H1[2], bcc);
                    bcc = pkfma(whh1p[3], H1[3], bcc);
                    bcc = pkfma(whh1p[4], H1[4], bcc);
                    const float s1 = (b1c + bcc.x) + bcc.y;
                    if      (k == 0) c0 = s1;
                    else if (k == 1) c1 = s1;
                    else if (k == 2) c2 = s1;
                    else             c3 = s1;
                    h1own = fast_tanh(s1);
                    h1b[lane] = h1own;
                    __builtin_amdgcn_wave_barrier();
                    const float4 q0 = *(const float4*)(h1b);
                    const float4 q1 = *(const float4*)(h1b + 4);
                    const f2     q2 = *(const f2*)(h1b + 8);
                    H1[0] = f2{q0.x, q0.y}; H1[1] = f2{q0.z, q0.w};
                    H1[2] = f2{q1.x, q1.y}; H1[3] = f2{q1.z, q1.w};
                    H1[4] = q2;
                }
                // c_k = out(tb+k-1); store previous aligned quad, carry rest
                if (olane && m >= 2)
                    *(float4*)(orow + tb - 4) = make_float4(P1, P2, P3, c0);
                P1 = c1; P2 = c2; P3 = c3;
            }
        }
        __syncthreads();
    }

    if (!isA) {
        // epilogue: out(2047) = rider dot with final H1 = h1(2047)
        f2 cc = pkmul(whh1p[0], H1[0]);
        cc = pkfma(whh1p[1], H1[1], cc);
        cc = pkfma(whh1p[2], H1[2], cc);
        cc = pkfma(whh1p[3], H1[3], cc);
        cc = pkfma(whh1p[4], H1[4], cc);
        const float ofin = (b1c + cc.x) + cc.y;
        if (olane)
            *(float4*)(orow + TT - 4) = make_float4(P1, P2, P3, ofin);
    }

    // final hidden state: [2, B, H] appended after B*T outputs
    if (isA) {
        if (act) out[(size_t)BB*TT + (size_t)row*HID + lane] = h0own;
    } else {
        if (act) out[(size_t)BB*TT + (size_t)BB*HID + (size_t)row*HID + lane] = h1own;
    }
}

extern "C" void kernel_launch(void* const* d_in, const int* in_sizes, int n_in,
                              void* d_out, int out_size, void* d_ws, size_t ws_size,
                              hipStream_t stream) {
    const float* x    = (const float*)d_in[0];
    const float* hs   = (const float*)d_in[1];
    const float* Wih0 = (const float*)d_in[2];
    const float* Whh0 = (const float*)d_in[3];
    const float* bih0 = (const float*)d_in[4];
    const float* bhh0 = (const float*)d_in[5];
    const float* Wih1 = (const float*)d_in[6];
    const float* Whh1 = (const float*)d_in[7];
    const float* bih1 = (const float*)d_in[8];
    const float* bhh1 = (const float*)d_in[9];
    const float* Wout = (const float*)d_in[10];
    const float* bout = (const float*)d_in[11];
    float* out = (float*)d_out;

    dim3 grid(BB / 4), block(128);
    hipLaunchKernelGGL(rnn_kernel, grid, block, 0, stream,
        x, hs, Wih0, Whh0, bih0, bhh0, Wih1, Whh1, bih1, bhh1, Wout, bout, out);
}